// Round 1
// baseline (410.922 us; speedup 1.0000x reference)
//
#include <hip/hip_runtime.h>
#include <cstdint>
#include <cstddef>

#define N_TOK 32768
#define DIM   1024
#define NE    64
#define RPB   64          // rows per block (= lanes)
#define KHALF 512         // k range per wave
#define CHUNK 32          // k per staged chunk
#define NCHUNK (KHALF / CHUNK)   // 16

// global -> LDS direct DMA, 16B per lane; LDS dest = wave-uniform base + lane*16
__device__ __forceinline__ void gload16(const float* g, float* l) {
  __builtin_amdgcn_global_load_lds(
      (const __attribute__((address_space(1))) uint32_t*)g,
      (__attribute__((address_space(3))) uint32_t*)l, 16, 0, 0);
}

__global__ __launch_bounds__(512, 4) void router_kernel(
    const float* __restrict__ x, const float* __restrict__ W,
    const float* __restrict__ bias, float* __restrict__ probs,
    float* __restrict__ idxo) {
  // x staging: [half][buf][row 64][k 32], quad-swizzled within each row's 128B
  __shared__ __align__(1024) float xs[2][2][RPB][CHUNK];   // 32 KB
  __shared__ float  red[4][RPB][16];                       // 16 KB (k-reduction)
  __shared__ float4 ex[4][RPB];                            // 4 KB (per-group top2)
  __shared__ float4 ex2[RPB];                              // 1 KB (final result bcast)

  const int tid  = threadIdx.x;
  const int lane = tid & 63;
  const int w    = __builtin_amdgcn_readfirstlane(tid >> 6); // 0..7
  const int g    = w & 3;        // expert group: experts g*16 .. g*16+15
  const int h    = w >> 2;       // k half: k in [h*512, h*512+512)
  const int r0   = blockIdx.x * RPB;

  // Force a formally-divergent zero so W addresses are VGPR-based ->
  // compiler must emit global_load_dwordx4 (VMEM/vmcnt path) instead of
  // s_load (SMEM). SMEM is modeled out-of-order and shares lgkmcnt with the
  // ds_read x-loads, forcing lgkmcnt(0) full drains every kk-group — that
  // serialization was the dominant stall (VALUBusy 27%).
  int vzero;
  asm volatile("v_mov_b32 %0, 0" : "=v"(vzero));

  // stage chunk cc of half h into buffer cc&1. 8 KB; 8 DMA instrs split 2/wave
  // LDS slot s (0..7) of row r holds global quad (s ^ (r&7))  [bank swizzle]
  auto stage = [&](int cc) {
    const int buf = cc & 1;
    float* base = &xs[h][buf][0][0];
    const int k0 = h * KHALF + cc * CHUNK;
#pragma unroll
    for (int jj = 0; jj < 2; ++jj) {
      const int j = 2 * g + jj;                 // instr slot 0..7 (rows 8j..8j+7)
      const int row = 8 * j + (lane >> 3);      // row&7 == lane>>3
      const int sq  = (lane & 7) ^ (lane >> 3); // source global quad for this slot
      gload16(x + (size_t)(r0 + row) * DIM + k0 + (sq << 2),
              base + j * 256);
    }
  };

  float acc[16];
#pragma unroll
  for (int e = 0; e < 16; ++e) acc[e] = 0.0f;

  stage(0);

  for (int cc = 0; cc < NCHUNK; ++cc) {
    __syncthreads();                    // drains DMA for chunk cc, protects bufs
    if (cc + 1 < NCHUNK) stage(cc + 1);

    const int buf = cc & 1;
    const float* xb = &xs[h][buf][0][0] + lane * CHUNK;   // this lane's row
    // W chunk base, made divergent (vzero) -> vector loads, pipelined on vmcnt
    const float* Wc = W + (size_t)(h * KHALF + cc * CHUNK) * NE + g * 16 + vzero;

    float4 xq = make_float4(0.f, 0.f, 0.f, 0.f);
#pragma unroll
    for (int kk = 0; kk < CHUNK; ++kk) {
      if ((kk & 3) == 0) {
        const int slot = (kk >> 2) ^ (lane & 7);          // undo swizzle
        xq = *(const float4*)(xb + (slot << 2));
      }
      const float xc = ((kk & 3) == 0) ? xq.x
                     : ((kk & 3) == 1) ? xq.y
                     : ((kk & 3) == 2) ? xq.z : xq.w;
      // 16 consecutive floats of W row kk via 4x global_load_dwordx4
      // (wave-uniform address -> 1 cacheline request, L1/L2-hot)
      const float4* Wk = (const float4*)(Wc + (size_t)kk * NE);
      const float4 w0 = Wk[0];
      const float4 w1 = Wk[1];
      const float4 w2 = Wk[2];
      const float4 w3 = Wk[3];
      acc[ 0] = fmaf(w0.x, xc, acc[ 0]);
      acc[ 1] = fmaf(w0.y, xc, acc[ 1]);
      acc[ 2] = fmaf(w0.z, xc, acc[ 2]);
      acc[ 3] = fmaf(w0.w, xc, acc[ 3]);
      acc[ 4] = fmaf(w1.x, xc, acc[ 4]);
      acc[ 5] = fmaf(w1.y, xc, acc[ 5]);
      acc[ 6] = fmaf(w1.z, xc, acc[ 6]);
      acc[ 7] = fmaf(w1.w, xc, acc[ 7]);
      acc[ 8] = fmaf(w2.x, xc, acc[ 8]);
      acc[ 9] = fmaf(w2.y, xc, acc[ 9]);
      acc[10] = fmaf(w2.z, xc, acc[10]);
      acc[11] = fmaf(w2.w, xc, acc[11]);
      acc[12] = fmaf(w3.x, xc, acc[12]);
      acc[13] = fmaf(w3.y, xc, acc[13]);
      acc[14] = fmaf(w3.z, xc, acc[14]);
      acc[15] = fmaf(w3.w, xc, acc[15]);
    }
  }

  // ---- k-reduction: half-1 waves publish, half-0 waves accumulate ----
  __syncthreads();
  if (h == 1) {
#pragma unroll
    for (int q = 0; q < 4; ++q)
      *(float4*)&red[g][lane][q * 4] = make_float4(acc[q*4+0], acc[q*4+1],
                                                   acc[q*4+2], acc[q*4+3]);
  }
  __syncthreads();

  if (h == 0) {
#pragma unroll
    for (int q = 0; q < 4; ++q) {
      float4 r = *(const float4*)&red[g][lane][q * 4];
      acc[q*4+0] += r.x; acc[q*4+1] += r.y; acc[q*4+2] += r.z; acc[q*4+3] += r.w;
    }
    // bias (uniform scalar loads) then local top-2 of this 16-expert group
#pragma unroll
    for (int e = 0; e < 16; ++e) acc[e] += bias[g * 16 + e];

    float v1, v2; int j1, j2;
    if (acc[1] > acc[0]) { v1 = acc[1]; j1 = 1; v2 = acc[0]; j2 = 0; }
    else                 { v1 = acc[0]; j1 = 0; v2 = acc[1]; j2 = 1; }
#pragma unroll
    for (int e = 2; e < 16; ++e) {
      if (acc[e] > v1)      { v2 = v1; j2 = j1; v1 = acc[e]; j1 = e; }
      else if (acc[e] > v2) { v2 = acc[e]; j2 = e; }
    }
    ex[g][lane] = make_float4(v1, v2, (float)(g * 16 + j1), (float)(g * 16 + j2));
  }
  __syncthreads();

  if (w == 0) {   // merge the 4 groups (ascending g => strict '>' keeps lower idx)
    float4 m = ex[0][lane];
    float V1 = m.x, V2 = m.y, J1 = m.z, J2 = m.w;
#pragma unroll
    for (int gg = 1; gg < 4; ++gg) {
      float4 u = ex[gg][lane];
      if (u.x > V1) {
        bool s = (u.y > V1);
        V2 = s ? u.y : V1; J2 = s ? u.w : J1;
        V1 = u.x; J1 = u.z;
      } else if (u.x > V2) { V2 = u.x; J2 = u.z; }
    }
    const float e2 = __expf(V2 - V1);
    const float p1 = 1.0f / (1.0f + e2);
    const float p2 = e2 * p1;
    ex2[lane] = make_float4(J1, J2, p1, p2);
    float2 oi; oi.x = J1; oi.y = J2;
    *(float2*)(idxo + (size_t)(r0 + lane) * 2) = oi;
  }
  __syncthreads();

  if (h == 0) {   // scatter probs: each group-wave writes its 16-column slice
    float4 f = ex2[lane];
    const int ij1 = (int)f.x, ij2 = (int)f.y;
    float* op = probs + (size_t)(r0 + lane) * NE + g * 16;
#pragma unroll
    for (int q = 0; q < 4; ++q) {
      float4 o;
      const int e0 = g * 16 + q * 4;
      o.x = (e0 + 0 == ij1) ? f.z : (e0 + 0 == ij2) ? f.w : 0.0f;
      o.y = (e0 + 1 == ij1) ? f.z : (e0 + 1 == ij2) ? f.w : 0.0f;
      o.z = (e0 + 2 == ij1) ? f.z : (e0 + 2 == ij2) ? f.w : 0.0f;
      o.w = (e0 + 3 == ij1) ? f.z : (e0 + 3 == ij2) ? f.w : 0.0f;
      *(float4*)(op + q * 4) = o;
    }
  }
}

extern "C" void kernel_launch(void* const* d_in, const int* in_sizes, int n_in,
                              void* d_out, int out_size, void* d_ws, size_t ws_size,
                              hipStream_t stream) {
  (void)in_sizes; (void)n_in; (void)out_size; (void)d_ws; (void)ws_size;
  const float* x = (const float*)d_in[0];
  const float* W = (const float*)d_in[1];
  const float* b = (const float*)d_in[2];
  float* out  = (float*)d_out;
  float* idxo = out + (size_t)N_TOK * NE;   // indices chunk follows probs chunk

  dim3 grid(N_TOK / RPB);   // 512 blocks
  dim3 block(512);
  hipLaunchKernelGGL(router_kernel, grid, block, 0, stream, x, W, b, out, idxo);
}

// Round 2
// 251.817 us; speedup vs baseline: 1.6318x; 1.6318x over previous
//
#include <hip/hip_runtime.h>
#include <cstdint>
#include <cstddef>

#define N_TOK 32768
#define DIM   1024
#define NE    64
#define RPB   64          // rows per block (= lanes)
#define KHALF 512         // k range per wave
#define CHUNK 32          // k per staged chunk
#define NCHUNK (KHALF / CHUNK)   // 16

// global -> LDS direct DMA, 16B per lane; LDS dest = wave-uniform base + lane*16
__device__ __forceinline__ void gload16(const float* g, float* l) {
  __builtin_amdgcn_global_load_lds(
      (const __attribute__((address_space(1))) uint32_t*)g,
      (__attribute__((address_space(3))) uint32_t*)l, 16, 0, 0);
}

__global__ __launch_bounds__(512, 4) void router_kernel(
    const float* __restrict__ x, const float* __restrict__ W,
    const float* __restrict__ bias, float* __restrict__ probs,
    float* __restrict__ idxo) {
  // 64 KB LDS total (2 blocks/CU):
  //   [    0, 32768) x staging  [half][buf][row 64][k 32], quad-swizzled
  //   [32768, 65536) W staging  [buf][half][kk 32][e 64], linear
  // Epilogue aliases [0, 21504) (x staging is dead by then; barrier-separated):
  //   red [4][64][16] at 0, ex [4][64] float4 at 16384, ex2 [64] float4 at 20480
  __shared__ __align__(1024) unsigned char smem[65536];
  float*  xs  = (float*)smem;
  float*  ws  = (float*)(smem + 32768);
  float*  red = (float*)smem;
  float4* ex  = (float4*)(smem + 16384);
  float4* ex2 = (float4*)(smem + 20480);

  const int tid  = threadIdx.x;
  const int lane = tid & 63;
  const int w    = __builtin_amdgcn_readfirstlane(tid >> 6); // 0..7
  const int g    = w & 3;        // expert group: experts g*16 .. g*16+15
  const int h    = w >> 2;       // k half: k in [h*512, h*512+512)
  const int r0   = blockIdx.x * RPB;

  // stage chunk cc of half h into buffer cc&1.
  // x: 8 KB/half, 8 DMA instrs split 2/wave; LDS slot s of row r holds
  //    global quad (s ^ (r&7))  [bank swizzle for the strided ds_read]
  // W: 8 KB/half, contiguous rows W[k0..k0+31][0..63], linear dest (broadcast
  //    reads can't bank-conflict, no swizzle needed)
  auto stage = [&](int cc) {
    const int buf = cc & 1;
    const int k0  = h * KHALF + cc * CHUNK;
    float* xbase = xs + (h * 2 + buf) * (RPB * CHUNK);
    float* wbase = ws + (buf * 2 + h) * (CHUNK * NE);
    const float* wsrc = W + (size_t)k0 * NE;
#pragma unroll
    for (int jj = 0; jj < 2; ++jj) {
      const int j   = 2 * g + jj;               // instr slot 0..7
      const int row = 8 * j + (lane >> 3);      // rows 8j..8j+7
      const int sq  = (lane & 7) ^ (lane >> 3); // source global quad (swizzle)
      gload16(x + (size_t)(r0 + row) * DIM + k0 + (sq << 2), xbase + j * 256);
      gload16(wsrc + j * 256 + lane * 4,                     wbase + j * 256);
    }
  };

  float acc[16];
#pragma unroll
  for (int e = 0; e < 16; ++e) acc[e] = 0.0f;

  stage(0);

  for (int cc = 0; cc < NCHUNK; ++cc) {
    __syncthreads();                    // drains DMA for chunk cc, protects bufs
    if (cc + 1 < NCHUNK) stage(cc + 1);

    const int buf = cc & 1;
    const float* xb = xs + (h * 2 + buf) * (RPB * CHUNK) + lane * CHUNK;
    const float* wb = ws + (buf * 2 + h) * (CHUNK * NE) + g * 16;

    float4 xq = make_float4(0.f, 0.f, 0.f, 0.f);
#pragma unroll
    for (int kk = 0; kk < CHUNK; ++kk) {
      if ((kk & 3) == 0) {
        const int slot = (kk >> 2) ^ (lane & 7);          // undo swizzle
        xq = *(const float4*)(xb + (slot << 2));
      }
      const float xc = ((kk & 3) == 0) ? xq.x
                     : ((kk & 3) == 1) ? xq.y
                     : ((kk & 3) == 2) ? xq.z : xq.w;
      // W row kk: 16 floats via 4x uniform-address ds_read_b128 (broadcast).
      // All-DS lgkm => in-order => compiler pipelines with counted lgkmcnt.
      const float4* Wk = (const float4*)(wb + kk * NE);
      const float4 w0 = Wk[0];
      const float4 w1 = Wk[1];
      const float4 w2 = Wk[2];
      const float4 w3 = Wk[3];
      acc[ 0] = fmaf(w0.x, xc, acc[ 0]);
      acc[ 1] = fmaf(w0.y, xc, acc[ 1]);
      acc[ 2] = fmaf(w0.z, xc, acc[ 2]);
      acc[ 3] = fmaf(w0.w, xc, acc[ 3]);
      acc[ 4] = fmaf(w1.x, xc, acc[ 4]);
      acc[ 5] = fmaf(w1.y, xc, acc[ 5]);
      acc[ 6] = fmaf(w1.z, xc, acc[ 6]);
      acc[ 7] = fmaf(w1.w, xc, acc[ 7]);
      acc[ 8] = fmaf(w2.x, xc, acc[ 8]);
      acc[ 9] = fmaf(w2.y, xc, acc[ 9]);
      acc[10] = fmaf(w2.z, xc, acc[10]);
      acc[11] = fmaf(w2.w, xc, acc[11]);
      acc[12] = fmaf(w3.x, xc, acc[12]);
      acc[13] = fmaf(w3.y, xc, acc[13]);
      acc[14] = fmaf(w3.z, xc, acc[14]);
      acc[15] = fmaf(w3.w, xc, acc[15]);
    }
  }

  // ---- k-reduction: half-1 waves publish, half-0 waves accumulate ----
  __syncthreads();     // also retires last chunk's x/W reads before aliasing
  if (h == 1) {
#pragma unroll
    for (int q = 0; q < 4; ++q)
      *(float4*)(red + (g * 64 + lane) * 16 + q * 4) =
          make_float4(acc[q*4+0], acc[q*4+1], acc[q*4+2], acc[q*4+3]);
  }
  __syncthreads();

  if (h == 0) {
#pragma unroll
    for (int q = 0; q < 4; ++q) {
      float4 r = *(const float4*)(red + (g * 64 + lane) * 16 + q * 4);
      acc[q*4+0] += r.x; acc[q*4+1] += r.y; acc[q*4+2] += r.z; acc[q*4+3] += r.w;
    }
    // bias (uniform scalar loads) then local top-2 of this 16-expert group
#pragma unroll
    for (int e = 0; e < 16; ++e) acc[e] += bias[g * 16 + e];

    float v1, v2; int j1, j2;
    if (acc[1] > acc[0]) { v1 = acc[1]; j1 = 1; v2 = acc[0]; j2 = 0; }
    else                 { v1 = acc[0]; j1 = 0; v2 = acc[1]; j2 = 1; }
#pragma unroll
    for (int e = 2; e < 16; ++e) {
      if (acc[e] > v1)      { v2 = v1; j2 = j1; v1 = acc[e]; j1 = e; }
      else if (acc[e] > v2) { v2 = acc[e]; j2 = e; }
    }
    ex[g * 64 + lane] = make_float4(v1, v2, (float)(g * 16 + j1),
                                            (float)(g * 16 + j2));
  }
  __syncthreads();

  if (w == 0) {   // merge the 4 groups (ascending g => strict '>' keeps lower idx)
    float4 m = ex[lane];
    float V1 = m.x, V2 = m.y, J1 = m.z, J2 = m.w;
#pragma unroll
    for (int gg = 1; gg < 4; ++gg) {
      float4 u = ex[gg * 64 + lane];
      if (u.x > V1) {
        bool s = (u.y > V1);
        V2 = s ? u.y : V1; J2 = s ? u.w : J1;
        V1 = u.x; J1 = u.z;
      } else if (u.x > V2) { V2 = u.x; J2 = u.z; }
    }
    const float e2 = __expf(V2 - V1);
    const float p1 = 1.0f / (1.0f + e2);
    const float p2 = e2 * p1;
    ex2[lane] = make_float4(J1, J2, p1, p2);
    float2 oi; oi.x = J1; oi.y = J2;
    *(float2*)(idxo + (size_t)(r0 + lane) * 2) = oi;
  }
  __syncthreads();

  if (h == 0) {   // scatter probs: each group-wave writes its 16-column slice
    float4 f = ex2[lane];
    const int ij1 = (int)f.x, ij2 = (int)f.y;
    float* op = probs + (size_t)(r0 + lane) * NE + g * 16;
#pragma unroll
    for (int q = 0; q < 4; ++q) {
      float4 o;
      const int e0 = g * 16 + q * 4;
      o.x = (e0 + 0 == ij1) ? f.z : (e0 + 0 == ij2) ? f.w : 0.0f;
      o.y = (e0 + 1 == ij1) ? f.z : (e0 + 1 == ij2) ? f.w : 0.0f;
      o.z = (e0 + 2 == ij1) ? f.z : (e0 + 2 == ij2) ? f.w : 0.0f;
      o.w = (e0 + 3 == ij1) ? f.z : (e0 + 3 == ij2) ? f.w : 0.0f;
      *(float4*)(op + q * 4) = o;
    }
  }
}

extern "C" void kernel_launch(void* const* d_in, const int* in_sizes, int n_in,
                              void* d_out, int out_size, void* d_ws, size_t ws_size,
                              hipStream_t stream) {
  (void)in_sizes; (void)n_in; (void)out_size; (void)d_ws; (void)ws_size;
  const float* x = (const float*)d_in[0];
  const float* W = (const float*)d_in[1];
  const float* b = (const float*)d_in[2];
  float* out  = (float*)d_out;
  float* idxo = out + (size_t)N_TOK * NE;   // indices chunk follows probs chunk

  dim3 grid(N_TOK / RPB);   // 512 blocks
  dim3 block(512);
  hipLaunchKernelGGL(router_kernel, grid, block, 0, stream, x, W, b, out, idxo);
}